// Round 13
// baseline (249.963 us; speedup 1.0000x reference)
//
#include <hip/hip_runtime.h>

// LBP 'var' texture loss, MI355X. [16,3,512,512] f32.
// A/B run the identical 52-tap stencil -> packed fp32 over {A,B} pairs.
// Evidence ledger: r2 scalar 75us VALU98% -> r3 packed 57us VALU62% (VALU
// cycles halved as predicted; ~35us VALU-equiv constant across r3/r7/r12).
// r12: TILE_Y=32@512thr regressed (92us, VALU 37%) -> revert to 16/256.
// r13: SINGLE-asm 20-operand window pin. r5/r7's per-f4 pins let the
// scheduler interleave load/pin/consume one value at a time (VGPR stayed 48).
// One asm with all 20 f4s as "+v" forces: 20x ds_read_b128 -> one lgkmcnt(0)
// -> 336 stall-free v_pk_fma_f32. Costs ~104-128 VGPR -> 16 waves/CU (50%),
// trading TLP for ILP; LDS 11.8KB no longer binds occupancy.

typedef float f2 __attribute__((ext_vector_type(2)));
typedef float f4 __attribute__((ext_vector_type(4)));

#define IMG_H 512
#define IMG_W 512
#define TILE_X 64
#define TILE_Y 16
#define LDS_H  20   // TILE_Y + 4 halo rows
#define LDS_CP 72   // pair-cols per row: [bx*64-4, bx*64+68)
#define LDS_SP 74   // padded pair stride (592 B = 37*16 -> b128-aligned)

// Circle offsets, exactly matching np.round(±2*sin/cos(2*pi*i/16), 8)
constexpr double RPV[16] = {
   0.0,        -0.76536686, -1.41421356, -1.84775907,
  -2.0,        -1.84775907, -1.41421356, -0.76536686,
   0.0,         0.76536686,  1.41421356,  1.84775907,
   2.0,         1.84775907,  1.41421356,  0.76536686
};
constexpr double CPV[16] = {
   2.0,         1.84775907,  1.41421356,  0.76536686,
   0.0,        -0.76536686, -1.41421356, -1.84775907,
  -2.0,        -1.84775907, -1.41421356, -0.76536686,
   0.0,         0.76536686,  1.41421356,  1.84775907
};

constexpr int cfloor(double x) {
  int i = (int)x;
  return (x < (double)i) ? i - 1 : i;
}

__device__ __forceinline__ f2 splat(float x) { f2 r; r.x = x; r.y = x; return r; }

// One circle point, packed over {A,B}. Window w: 5 rows x 8 f2.
// Tap order 00,01,10,11, w<=1e-12 skipped, exactly as the reference.
template<int I>
__device__ __forceinline__ void lbp_point(const f2 (&w)[5][8], int px,
                                          f2& s1, f2& s2) {
  constexpr double rp = RPV[I], cp = CPV[I];
  constexpr int fr = cfloor(rp), fc = cfloor(cp);
  constexpr double tr = rp - (double)fr, tc = cp - (double)fc;
  constexpr double W00 = (1.0 - tr) * (1.0 - tc);
  constexpr double W01 = (1.0 - tr) * tc;
  constexpr double W10 = tr * (1.0 - tc);
  constexpr double W11 = tr * tc;
  f2 v = splat(0.0f);
  if constexpr (W00 > 1e-12)
    v = __builtin_elementwise_fma(splat((float)W00), w[fr + 2][px + fc + 2], v);
  if constexpr (W01 > 1e-12)
    v = __builtin_elementwise_fma(splat((float)W01), w[fr + 2][px + fc + 3], v);
  if constexpr (W10 > 1e-12)
    v = __builtin_elementwise_fma(splat((float)W10), w[fr + 3][px + fc + 2], v);
  if constexpr (W11 > 1e-12)
    v = __builtin_elementwise_fma(splat((float)W11), w[fr + 3][px + fc + 3], v);
  s1 = s1 + v;
  s2 = __builtin_elementwise_fma(v, v, s2);
}

__device__ __forceinline__ void lbp_all16(const f2 (&w)[5][8], int px,
                                          f2& s1, f2& s2) {
  lbp_point<0>(w, px, s1, s2);  lbp_point<1>(w, px, s1, s2);
  lbp_point<2>(w, px, s1, s2);  lbp_point<3>(w, px, s1, s2);
  lbp_point<4>(w, px, s1, s2);  lbp_point<5>(w, px, s1, s2);
  lbp_point<6>(w, px, s1, s2);  lbp_point<7>(w, px, s1, s2);
  lbp_point<8>(w, px, s1, s2);  lbp_point<9>(w, px, s1, s2);
  lbp_point<10>(w, px, s1, s2); lbp_point<11>(w, px, s1, s2);
  lbp_point<12>(w, px, s1, s2); lbp_point<13>(w, px, s1, s2);
  lbp_point<14>(w, px, s1, s2); lbp_point<15>(w, px, s1, s2);
}

__global__ __launch_bounds__(256)
void lbp_loss_kernel(const float* __restrict__ A, const float* __restrict__ B,
                     double* acc) {
  __shared__ __align__(16) f2 tile[LDS_H][LDS_SP];
  __shared__ double bsum[4];

  const int tid = threadIdx.x;
  const int bx = blockIdx.x, by = blockIdx.y, z = blockIdx.z;
  const int row0 = by * TILE_Y - 2;
  const int col0 = bx * TILE_X - 4;   // aligned-float4 halo start
  const size_t ibase = (size_t)z * (IMG_H * IMG_W);

  // Stage interleaved {A,B} pairs: 18 aligned float4-quads per row x 20 rows.
  // A quad is fully inside [0,512) or fully outside -> single bounds check.
  const int QUADS = LDS_CP / 4;            // 18
  const int SLOTS = LDS_H * QUADS;         // 360 -> 2 iterations at 256 thr
  for (int idx = tid; idx < SLOTS; idx += 256) {
    const int r = idx / QUADS;
    const int q = idx - r * QUADS;
    const int gr = row0 + r;
    const int gc = col0 + q * 4;
    f4 a = {0.f, 0.f, 0.f, 0.f};
    f4 b = {0.f, 0.f, 0.f, 0.f};
    if ((unsigned)gr < (unsigned)IMG_H && (unsigned)gc < (unsigned)IMG_W) {
      const size_t off = ibase + (size_t)gr * IMG_W + gc;
      a = *(const f4*)&A[off];
      b = *(const f4*)&B[off];
    }
    f2* dst = &tile[r][q * 4];
    dst[0] = f2{a.x, b.x};
    dst[1] = f2{a.y, b.y};
    dst[2] = f2{a.z, b.z};
    dst[3] = f2{a.w, b.w};
  }
  __syncthreads();

  const int tx = tid & 15;   // 16 threads across, 4 px each -> 64 cols
  const int ty = tid >> 4;   // 16 rows

  // 5x8 f2 window, rows ty..ty+4, pair-cols tx*4+2..tx*4+9.
  // Byte offset (74r + 4tx + 2)*8 is 16B-aligned -> 4x ds_read_b128 per row.
  f4 wq[5][4];
  #pragma unroll
  for (int r = 0; r < 5; ++r) {
    const f4* lp = (const f4*)&tile[ty + r][tx * 4 + 2];
    wq[r][0] = lp[0]; wq[r][1] = lp[1]; wq[r][2] = lp[2]; wq[r][3] = lp[3];
  }
  // ONE asm with ALL 20 f4s as "+v": every ds_read must complete before this
  // point (single lgkmcnt wait) and every tap below reads the asm's register
  // outputs -> the whole 80-VGPR window is simultaneously resident. (r5/r7's
  // per-value pins allowed one-value-at-a-time interleaving: VGPR stayed 48.)
  asm volatile(""
    : "+v"(wq[0][0]), "+v"(wq[0][1]), "+v"(wq[0][2]), "+v"(wq[0][3]),
      "+v"(wq[1][0]), "+v"(wq[1][1]), "+v"(wq[1][2]), "+v"(wq[1][3]),
      "+v"(wq[2][0]), "+v"(wq[2][1]), "+v"(wq[2][2]), "+v"(wq[2][3]),
      "+v"(wq[3][0]), "+v"(wq[3][1]), "+v"(wq[3][2]), "+v"(wq[3][3]),
      "+v"(wq[4][0]), "+v"(wq[4][1]), "+v"(wq[4][2]), "+v"(wq[4][3]));

  // Extract f2 lanes (sub-register aliases; no instructions).
  f2 w[5][8];
  #pragma unroll
  for (int r = 0; r < 5; ++r) {
    #pragma unroll
    for (int q = 0; q < 4; ++q) {
      w[r][2 * q]     = f2{wq[r][q].x, wq[r][q].y};
      w[r][2 * q + 1] = f2{wq[r][q].z, wq[r][q].w};
    }
  }

  float local = 0.0f;
  #pragma unroll
  for (int px = 0; px < 4; ++px) {
    f2 s1 = splat(0.0f), s2 = splat(0.0f);
    lbp_all16(w, px, s1, s2);
    f2 mean = s1 * 0.0625f;
    f2 var  = __builtin_elementwise_fma(-mean, mean, s2 * 0.0625f);
    const float d = var.x - var.y;
    local = fmaf(d, d, local);
  }

  // wave64 shuffle reduce -> 4 wave sums -> ONE fire-and-forget f64 atomic
  // per block (r2-proven ~free; r7 proved waiting on its return is fatal).
  #pragma unroll
  for (int off = 32; off > 0; off >>= 1)
    local += __shfl_down(local, off, 64);
  if ((tid & 63) == 0) bsum[tid >> 6] = (double)local;
  __syncthreads();
  if (tid == 0) {
    const double psum = bsum[0] + bsum[1] + bsum[2] + bsum[3];
    atomicAdd(acc, psum);   // return value intentionally unused
  }
}

__global__ void finalize_kernel(const double* __restrict__ acc,
                                float* __restrict__ out, double inv_n) {
  out[0] = (float)(acc[0] * inv_n);
}

extern "C" void kernel_launch(void* const* d_in, const int* in_sizes, int n_in,
                              void* d_out, int out_size, void* d_ws, size_t ws_size,
                              hipStream_t stream) {
  const float* A = (const float*)d_in[0];   // output
  const float* B = (const float*)d_in[1];   // target
  float* out = (float*)d_out;
  double* acc = (double*)d_ws;              // single f64 accumulator

  hipMemsetAsync(acc, 0, sizeof(double), stream);

  const int total = in_sizes[0];                 // 16*3*512*512 = 12,582,912
  const int BC = total / (IMG_H * IMG_W);        // 48
  dim3 grid(IMG_W / TILE_X, IMG_H / TILE_Y, BC); // (8, 32, 48) = 12288 blocks
  lbp_loss_kernel<<<grid, 256, 0, stream>>>(A, B, acc);
  finalize_kernel<<<1, 1, 0, stream>>>(acc, out, 1.0 / (double)total);
}